// Round 8
// baseline (186.462 us; speedup 1.0000x reference)
//
#include <hip/hip_runtime.h>
#include <math.h>

#define SEQ   3000
#define FDIM  64
// 999 sequential steps = 111 groups (g0..g110) x 9 steps.
// Packed-FP32 version: each lane advances TWO adjacent-f chains, (b,2k) and
// (b,2k+1), as ext_vector float2 -> v_pk_fma_f32/v_pk_mul_f32 on gfx950.
// One global_load_dwordx2 / global_store_dwordx2 covers both chains, so the
// R6/R7 asm pipeline (27 ld + 27 st per group, vmcnt(54), never 0) is
// unchanged. 64 blocks x 64 lanes: lane l -> b = 2*blk + (l>>5), f = 2*(l&31).

typedef float v2f __attribute__((ext_vector_type(2)));

#define PPW  0.23164189f                  // 0.3275911 * (1/sqrt(2))
#define B1c  0.127414796f                 // 0.5*0.254829592
#define B2c  (-0.142248368f)              // 0.5*-0.284496736
#define B3c  0.7107068705f                // 0.5*1.421413741
#define B4c  (-0.7265760135f)             // 0.5*-1.453152027
#define B5c  0.5307027145f                // 0.5*1.061405429
#define NL2E (-0.72134752044448170368f)   // -0.5*log2(e)

#define F2FMA(a, b, c) __builtin_elementwise_fma((v2f)(a), (v2f)(b), (v2f)(c))
#define F2ABS(a)       __builtin_elementwise_abs((v2f)(a))
#define F2MAX(a, b)    __builtin_elementwise_max((v2f)(a), (v2f)(b))

#define DECL27(p)  v2f p##0,p##1,p##2,p##3,p##4,p##5,p##6,p##7,p##8,p##9,     \
    p##10,p##11,p##12,p##13,p##14,p##15,p##16,p##17,p##18,p##19,p##20,p##21,  \
    p##22,p##23,p##24,p##25,p##26

#define TOUCH27(P) "+v"(P##0),"+v"(P##1),"+v"(P##2),"+v"(P##3),"+v"(P##4),    \
    "+v"(P##5),"+v"(P##6),"+v"(P##7),"+v"(P##8),"+v"(P##9),"+v"(P##10),       \
    "+v"(P##11),"+v"(P##12),"+v"(P##13),"+v"(P##14),"+v"(P##15),"+v"(P##16),  \
    "+v"(P##17),"+v"(P##18),"+v"(P##19),"+v"(P##20),"+v"(P##21),"+v"(P##22),  \
    "+v"(P##23),"+v"(P##24),"+v"(P##25),"+v"(P##26)

#define PF1(dst, p, OFF)                                                      \
    asm volatile("global_load_dwordx2 %0, %1, off offset:" #OFF               \
                 : "=v"(dst) : "v"(p) : "memory")
#define ST1(val, p, OFF)                                                      \
    asm volatile("global_store_dwordx2 %0, %1, off offset:" #OFF              \
                 :: "v"(p), "v"(val) : "memory")

// 27 x2-loads of one group; xc advances 9 rows (2304 B) per 9 loads so every
// offset immediate stays < 4096. Row stride = 256 B.
#define PF27(P) do {                                                          \
    PF1(P##0,  xc, 0);    PF1(P##1,  xc, 256);  PF1(P##2,  xc, 512);          \
    PF1(P##3,  xc, 768);  PF1(P##4,  xc, 1024); PF1(P##5,  xc, 1280);         \
    PF1(P##6,  xc, 1536); PF1(P##7,  xc, 1792); PF1(P##8,  xc, 2048);         \
    xc += 9 * FDIM;                                                           \
    PF1(P##9,  xc, 0);    PF1(P##10, xc, 256);  PF1(P##11, xc, 512);          \
    PF1(P##12, xc, 768);  PF1(P##13, xc, 1024); PF1(P##14, xc, 1280);         \
    PF1(P##15, xc, 1536); PF1(P##16, xc, 1792); PF1(P##17, xc, 2048);         \
    xc += 9 * FDIM;                                                           \
    PF1(P##18, xc, 0);    PF1(P##19, xc, 256);  PF1(P##20, xc, 512);          \
    PF1(P##21, xc, 768);  PF1(P##22, xc, 1024); PF1(P##23, xc, 1280);         \
    PF1(P##24, xc, 1536); PF1(P##25, xc, 1792); PF1(P##26, xc, 2048);         \
    xc += 9 * FDIM;                                                           \
} while (0)

// counted wait: P = load buffer about to be consumed; dataflow tie so its
// consumers cannot hoist above the wait (rule #18), plus a sched fence.
#define WAITVM(Nlit, P) do {                                                  \
    asm volatile("s_waitcnt vmcnt(" #Nlit ")" : TOUCH27(P) : : "memory");     \
    __builtin_amdgcn_sched_barrier(0);                                        \
} while (0)

// One scan step for BOTH chains (v2f). gelu(a) = relu(a) - |a|*[0.5*erfc(u)],
// u=|a|/sqrt(2); 0.5*erfc via halved A&S 7.1.26 with r = 1/(1 + PPW*|a|),
// tail = exp2(a^2 * NL2E). Stores issue directly from fresh state (VMEM
// stores latch data at issue).
#define GSTEP3(F0, F1, F2, u0, u1, u2) do {                                   \
    v2f a0 = F2FMA(s2, W02, F2FMA(s1, W01, F2FMA(s0, W00, Q0)));              \
    v2f a1 = F2FMA(s2, W12, F2FMA(s1, W11, F2FMA(s0, W10, Q1)));              \
    v2f a2 = F2FMA(s2, W22, F2FMA(s1, W21, F2FMA(s0, W20, Q2)));              \
    v2f m0 = (a0 * a0) * NL2E, m1 = (a1 * a1) * NL2E, m2 = (a2 * a2) * NL2E;  \
    v2f e0, e1, e2;                                                           \
    e0.x = __builtin_amdgcn_exp2f(m0.x); e0.y = __builtin_amdgcn_exp2f(m0.y); \
    e1.x = __builtin_amdgcn_exp2f(m1.x); e1.y = __builtin_amdgcn_exp2f(m1.y); \
    e2.x = __builtin_amdgcn_exp2f(m2.x); e2.y = __builtin_amdgcn_exp2f(m2.y); \
    v2f b0 = F2ABS(a0), b1 = F2ABS(a1), b2 = F2ABS(a2);                       \
    v2f d0 = F2FMA(PPW, b0, 1.0f), d1 = F2FMA(PPW, b1, 1.0f),                 \
        d2 = F2FMA(PPW, b2, 1.0f);                                            \
    v2f r0, r1, r2;                                                           \
    r0.x = __builtin_amdgcn_rcpf(d0.x); r0.y = __builtin_amdgcn_rcpf(d0.y);   \
    r1.x = __builtin_amdgcn_rcpf(d1.x); r1.y = __builtin_amdgcn_rcpf(d1.y);   \
    r2.x = __builtin_amdgcn_rcpf(d2.x); r2.y = __builtin_amdgcn_rcpf(d2.y);   \
    v2f p0 = F2FMA(B2c, r0, B1c), p1 = F2FMA(B2c, r1, B1c),                   \
        p2 = F2FMA(B2c, r2, B1c);                                             \
    v2f n0 = F2FMA(B4c, r0, B3c), n1 = F2FMA(B4c, r1, B3c),                   \
        n2 = F2FMA(B4c, r2, B3c);                                             \
    v2f rr0 = r0 * r0, rr1 = r1 * r1, rr2 = r2 * r2;                          \
    p0 = F2FMA(n0, rr0, p0); p1 = F2FMA(n1, rr1, p1); p2 = F2FMA(n2, rr2, p2);\
    v2f r40 = rr0 * rr0, r41 = rr1 * rr1, r42 = rr2 * rr2;                    \
    p0 = F2FMA(B5c, r40, p0); p1 = F2FMA(B5c, r41, p1);                       \
    p2 = F2FMA(B5c, r42, p2);                                                 \
    v2f er0 = (p0 * r0) * e0, er1 = (p1 * r1) * e1, er2 = (p2 * r2) * e2;     \
    v2f x0 = F2MAX(a0, 0.0f), x1 = F2MAX(a1, 0.0f), x2 = F2MAX(a2, 0.0f);     \
    s0 = F2FMA(-b0, er0, x0) + u0;                                            \
    s1 = F2FMA(-b1, er1, x1) + u1;                                            \
    s2 = F2FMA(-b2, er2, x2) + u2;                                            \
    ST1(s0, oc, F0); ST1(s1, oc, F1); ST1(s2, oc, F2);                        \
} while (0)

// one group of 9 steps; 27 asm x2-stores; oc advances 9 rows per 3 steps
#define COMPUTE_GRP(P) do {                                                   \
    GSTEP3(0, 256, 512,      P##0,  P##1,  P##2);                             \
    GSTEP3(768, 1024, 1280,  P##3,  P##4,  P##5);                             \
    GSTEP3(1536, 1792, 2048, P##6,  P##7,  P##8);                             \
    oc += 9 * FDIM;                                                           \
    GSTEP3(0, 256, 512,      P##9,  P##10, P##11);                            \
    GSTEP3(768, 1024, 1280,  P##12, P##13, P##14);                            \
    GSTEP3(1536, 1792, 2048, P##15, P##16, P##17);                            \
    oc += 9 * FDIM;                                                           \
    GSTEP3(0, 256, 512,      P##18, P##19, P##20);                            \
    GSTEP3(768, 1024, 1280,  P##21, P##22, P##23);                            \
    GSTEP3(1536, 1792, 2048, P##24, P##25, P##26);                            \
    oc += 9 * FDIM;                                                           \
} while (0)

__global__ __launch_bounds__(64, 1) void scan_kernel(
    const float* __restrict__ x,
    const float* __restrict__ w,
    const float* __restrict__ bias,
    float* __restrict__ out)
{
    const int lane = threadIdx.x;
    const int b  = blockIdx.x * 2 + (lane >> 5);   // 2 batches per wave
    const int fp = (lane & 31) * 2;                // adjacent f pair

    // broadcast weights/bias into v2f (both packed lanes use the same W)
    const v2f W00 = w[0], W01 = w[1], W02 = w[2];
    const v2f W10 = w[3], W11 = w[4], W12 = w[5];
    const v2f W20 = w[6], W21 = w[7], W22 = w[8];
    const v2f Q0 = bias[0], Q1 = bias[1], Q2 = bias[2];

    const float* __restrict__ xp = x   + (size_t)b * (SEQ * FDIM) + fp;
    float*       __restrict__ op = out + (size_t)b * (SEQ * FDIM) + fp;

    // head: plain x2 loads, consumed by the touch so the compiler's own vmcnt
    // wait lands HERE (before any asm loads are outstanding)
    v2f s0 = *(const v2f*)(xp + 0 * FDIM);
    v2f s1 = *(const v2f*)(xp + 1 * FDIM);
    v2f s2 = *(const v2f*)(xp + 2 * FDIM);
    asm volatile("" : "+v"(s0), "+v"(s1), "+v"(s2));
    ST1(s0, op, 0); ST1(s1, op, 256); ST1(s2, op, 512);   // 3 asm stores

    const float* xc = xp + 3 * FDIM;
    float*       oc = op + 3 * FDIM;

    DECL27(LA); DECL27(LB);     // load double-buffer (asm outputs)

    PF27(LA);                   // g0
    PF27(LB);                   // g1
    // outstanding: hst(3) + LA(27) + LB(27) = 57 -> vmcnt(27) retires hst+LA
    WAITVM(27, LA);

    // loop t: computes g=2t (LA) and g=2t+1 (LB); prefetches 2t+2, 2t+3
    #pragma unroll 1
    for (int t = 0; t < 54; ++t) {
        COMPUTE_GRP(LA);        // g = 2t      (27 stores)
        PF27(LA);               // g = 2t+2    (27 loads)
        // young 54 = st(2t) + LA(2t+2): all older retired -> LB(2t+1) ready
        WAITVM(54, LB);
        COMPUTE_GRP(LB);        // g = 2t+1
        PF27(LB);               // g = 2t+3
        WAITVM(54, LA);         // LA(2t+2) ready
    }

    // epilogue: g108 (in LA), g109 (in LB), g110
    COMPUTE_GRP(LA);            // g108
    PF27(LA);                   // g110
    WAITVM(54, LB);             // LB = g109 ready
    COMPUTE_GRP(LB);            // g109
    WAITVM(27, LA);             // young 27 = st(g109) -> LA = g110 ready
    COMPUTE_GRP(LA);            // g110
}

extern "C" void kernel_launch(void* const* d_in, const int* in_sizes, int n_in,
                              void* d_out, int out_size, void* d_ws, size_t ws_size,
                              hipStream_t stream) {
    const float* x    = (const float*)d_in[0];
    const float* w    = (const float*)d_in[1];
    const float* bias = (const float*)d_in[2];
    float* out        = (float*)d_out;

    hipLaunchKernelGGL(scan_kernel, dim3(64), dim3(FDIM), 0, stream,
                       x, w, bias, out);
}

// Round 9
// 61.862 us; speedup vs baseline: 3.0142x; 3.0142x over previous
//
#include <hip/hip_runtime.h>
#include <math.h>

#define SEQ   3000
#define FDIM  64
// 999 sequential steps = 111 groups (g0..g110) x 9 steps.
// CHANNEL-PARALLEL: each chain (b,f) is handled by a 4-lane quad; lane p
// computes channel p (lane 3 mirrors lane 2 -> same value, same address).
// Cross-channel state exchange via 2 full-rate v_mov_dpp quad_perm ops.
// Per chain-step per lane: ~21 VALU instrs (vs 56 single-lane) -> single-wave
// issue-cadence bound drops ~2.7x. 512 blocks x 64 threads = 512 waves,
// 16 chains/wave. Asm vmem pipeline as R6: double-buffered 9-deep prefetch,
// counted s_waitcnt vmcnt(N), never 0 in the loop.

#define PPW  0.23164189f                  // 0.3275911 / sqrt(2)
#define B1c  0.127414796f                 // 0.5*0.254829592
#define B2c  (-0.142248368f)              // 0.5*-0.284496736
#define B3c  0.7107068705f                // 0.5*1.421413741
#define B4c  (-0.7265760135f)             // 0.5*-1.453152027
#define B5c  0.5307027145f                // 0.5*1.061405429
#define NL2E (-0.72134752044448170368f)   // -0.5*log2(e)

// quad_perm ctrl: perm[0] | perm[1]<<2 | perm[2]<<4 | perm[3]<<6
// DPP1: lane p <- s_{p+1 mod 3}; lane3 mirrors lane2: [1,2,0,0] = 9
// DPP2: lane p <- s_{p+2 mod 3}; lane3 mirrors lane2: [2,0,1,1] = 82
#define DPPF(src, ctrl)                                                       \
    __builtin_bit_cast(float, __builtin_amdgcn_update_dpp(                    \
        0, __builtin_bit_cast(int, (src)), (ctrl), 0xf, 0xf, false))

#define DECL9(p) float p##0,p##1,p##2,p##3,p##4,p##5,p##6,p##7,p##8
#define TOUCH9(P) "+v"(P##0),"+v"(P##1),"+v"(P##2),"+v"(P##3),"+v"(P##4),     \
    "+v"(P##5),"+v"(P##6),"+v"(P##7),"+v"(P##8)

#define PF1(dst, p, OFF)                                                      \
    asm volatile("global_load_dword %0, %1, off offset:" #OFF                 \
                 : "=v"(dst) : "v"(p) : "memory")
#define ST1(val, p, OFF)                                                      \
    asm volatile("global_store_dword %0, %1, off offset:" #OFF                \
                 :: "v"(p), "v"(val) : "memory")

// 9 loads of one group for this lane's channel: rows 3t+3+p, stride 3 rows
// (768 B); xc bumps 9 rows (2304 B) per 3 loads so immediates stay < 4096.
#define PF9(P) do {                                                           \
    PF1(P##0, xc, 0); PF1(P##1, xc, 768); PF1(P##2, xc, 1536);                \
    xc += 9 * FDIM;                                                           \
    PF1(P##3, xc, 0); PF1(P##4, xc, 768); PF1(P##5, xc, 1536);                \
    xc += 9 * FDIM;                                                           \
    PF1(P##6, xc, 0); PF1(P##7, xc, 768); PF1(P##8, xc, 1536);                \
    xc += 9 * FDIM;                                                           \
} while (0)

// counted wait: P = load buffer about to be consumed (dataflow tie, rule #18)
#define WAITVM(Nlit, P) do {                                                  \
    asm volatile("s_waitcnt vmcnt(" #Nlit ")" : TOUCH9(P) : : "memory");      \
    __builtin_amdgcn_sched_barrier(0);                                        \
} while (0)

// one chain-step for THIS lane's channel:
//   d1,d2 = other channels' state (dpp); a = W[p,:].s + q;
//   gelu(a) = relu(a) - |a|*[0.5*erfc(|a|/sqrt2)]; s' = gelu + u; store.
#define GSTEP(F, u) do {                                                      \
    int si_ = __builtin_bit_cast(int, s);                                     \
    float d1_ = __builtin_bit_cast(float,                                     \
        __builtin_amdgcn_update_dpp(0, si_, 9,  0xf, 0xf, false));            \
    float d2_ = __builtin_bit_cast(float,                                     \
        __builtin_amdgcn_update_dpp(0, si_, 82, 0xf, 0xf, false));            \
    float a_ = fmaf(wA, s, q);                                                \
    a_ = fmaf(wB, d1_, a_);                                                   \
    a_ = fmaf(wC, d2_, a_);                                                   \
    float m_ = (a_ * a_) * NL2E;                                              \
    float e_ = __builtin_amdgcn_exp2f(m_);                                    \
    float ab_ = fabsf(a_);                                                    \
    float dd_ = fmaf(PPW, ab_, 1.0f);                                         \
    float r_ = __builtin_amdgcn_rcpf(dd_);                                    \
    float p_ = fmaf(B2c, r_, B1c);                                            \
    float n_ = fmaf(B4c, r_, B3c);                                            \
    float rr_ = r_ * r_;                                                      \
    p_ = fmaf(n_, rr_, p_);                                                   \
    float r4_ = rr_ * rr_;                                                    \
    p_ = fmaf(B5c, r4_, p_);                                                  \
    float er_ = (p_ * r_) * e_;                                               \
    s = fmaf(-ab_, er_, fmaxf(a_, 0.0f)) + u;                                 \
    ST1(s, oc, F);                                                            \
} while (0)

// one group = 9 steps; 9 asm stores; oc bumps 9 rows per 3 steps
#define COMPUTE_GRP(P) do {                                                   \
    GSTEP(0, P##0); GSTEP(768, P##1); GSTEP(1536, P##2);  oc += 9 * FDIM;     \
    GSTEP(0, P##3); GSTEP(768, P##4); GSTEP(1536, P##5);  oc += 9 * FDIM;     \
    GSTEP(0, P##6); GSTEP(768, P##7); GSTEP(1536, P##8);  oc += 9 * FDIM;     \
} while (0)

__global__ __launch_bounds__(64, 1) void scan_kernel(
    const float* __restrict__ x,
    const float* __restrict__ w,
    const float* __restrict__ bias,
    float* __restrict__ out)
{
    const int lane = threadIdx.x;
    const int g  = lane >> 2;                    // chain within wave (0..15)
    const int pr = lane & 3;
    const int p  = pr < 3 ? pr : 2;              // channel; lane3 mirrors ch2

    const int b = blockIdx.x >> 2;               // 512 blocks -> b = 0..127
    const int f = ((blockIdx.x & 3) << 4) + g;   // f = 0..63

    // per-lane weight row: a = wA*s_p + wB*s_{p+1} + wC*s_{p+2} + q
    const int p1 = (p + 1) == 3 ? 0 : p + 1;
    const int p2 = (p + 2) >= 3 ? p - 1 : p + 2;
    float wA = w[p * 3 + p];
    float wB = w[p * 3 + p1];
    float wC = w[p * 3 + p2];
    float q  = bias[p];

    const float* __restrict__ xp = x   + (size_t)b * (SEQ * FDIM) + (size_t)p * FDIM + f;
    float*       __restrict__ op = out + (size_t)b * (SEQ * FDIM) + (size_t)p * FDIM + f;

    // head: plain loads (state + weights), all consumed by a touch HERE so
    // the compiler's own waitcnt lands before any asm vmem is outstanding.
    float s = xp[0];
    asm volatile("" : "+v"(s), "+v"(wA), "+v"(wB), "+v"(wC), "+v"(q));
    ST1(s, op, 0);                               // head copy (1 asm store)

    const float* xc = xp + 3 * FDIM;             // first u for this channel
    float*       oc = op + 3 * FDIM;

    DECL9(LA); DECL9(LB);                        // load double-buffer

    PF9(LA);                                     // g0
    PF9(LB);                                     // g1
    // outstanding: hst(1) + LA(9) + LB(9) = 19 -> vmcnt(9) retires hst+LA
    WAITVM(9, LA);

    // loop t: computes g=2t (LA) and g=2t+1 (LB); prefetches 2t+2, 2t+3
    #pragma unroll 1
    for (int t = 0; t < 54; ++t) {
        COMPUTE_GRP(LA);        // g = 2t      (9 stores)
        PF9(LA);                // g = 2t+2    (9 loads)
        // young 18 = st(2t)(9) + LA(2t+2)(9) -> LB(2t+1) ready
        WAITVM(18, LB);
        COMPUTE_GRP(LB);        // g = 2t+1
        PF9(LB);                // g = 2t+3
        WAITVM(18, LA);         // LA(2t+2) ready
    }

    // epilogue: g108 (in LA), g109 (in LB), g110
    COMPUTE_GRP(LA);            // g108
    PF9(LA);                    // g110
    WAITVM(18, LB);             // LB = g109 ready
    COMPUTE_GRP(LB);            // g109
    WAITVM(9, LA);              // young 9 = st(g109) -> LA = g110 ready
    COMPUTE_GRP(LA);            // g110
}

extern "C" void kernel_launch(void* const* d_in, const int* in_sizes, int n_in,
                              void* d_out, int out_size, void* d_ws, size_t ws_size,
                              hipStream_t stream) {
    const float* x    = (const float*)d_in[0];
    const float* w    = (const float*)d_in[1];
    const float* bias = (const float*)d_in[2];
    float* out        = (float*)d_out;

    hipLaunchKernelGGL(scan_kernel, dim3(512), dim3(64), 0, stream,
                       x, w, bias, out);
}